// Round 1
// baseline (666.881 us; speedup 1.0000x reference)
//
#include <hip/hip_runtime.h>
#include <hip/hip_bf16.h>
#include <stdint.h>

#define DIMV 1910
#define KP   1920                       // padded K/N (multiple of 64)
#define PHI_F  1.6180339887498949f
#define BETA_F 0.3819660112501051f

typedef __attribute__((ext_vector_type(4))) float f32x4;
typedef __attribute__((ext_vector_type(8))) short bf16x8;

// async global->LDS, 16B per lane. LDS dest = wave-uniform base + lane*16.
__device__ __forceinline__ void gload_lds16(const void* g, void* lds) {
    __builtin_amdgcn_global_load_lds(
        (const __attribute__((address_space(1))) void*)(uintptr_t)g,
        (__attribute__((address_space(3))) void*)(uint32_t)(uintptr_t)lds,
        16, 0, 0);
}

__global__ void k_scatter(const int* __restrict__ ridx, const int* __restrict__ cidx,
                          const float* __restrict__ vals, float* __restrict__ Wd, int nz) {
    int i = blockIdx.x * 256 + threadIdx.x;
    if (i < nz) atomicAdd(Wd + (long)ridx[i] * DIMV + cidx[i], vals[i]);
}

// W' = W + PHI*I, padded to [KP][KP], bf16
__global__ void k_build_w(const float* __restrict__ Wd, short* __restrict__ Wb) {
    int k = blockIdx.x * 128 + threadIdx.x;   // 0..1919
    int n = blockIdx.y;                        // 0..1919
    float v = (n < DIMV && k < DIMV) ? Wd[(long)n * DIMV + k] : 0.f;
    if (n == k && n < DIMV) v += PHI_F;
    __hip_bfloat16 b = __float2bfloat16(v);
    Wb[(long)n * KP + k] = *reinterpret_cast<short*>(&b);
}

// x fp32 [M][1910] -> bf16 [M][1920] (zero-padded cols)
__global__ void k_conv_x(const float* __restrict__ x, short* __restrict__ xb) {
    int k = blockIdx.x * 128 + threadIdx.x;   // 0..1919
    int m = blockIdx.y;
    float v = (k < DIMV) ? x[(long)m * DIMV + k] : 0.f;
    __hip_bfloat16 b = __float2bfloat16(v);
    xb[(long)m * KP + k] = *reinterpret_cast<short*>(&b);
}

// C[m][n] = BETA * sum_k A[m][k]*B[n][k];  A:[M][KP] bf16, B:[1920][KP] bf16, C:[M][1910] fp32
// 128x128 tile, BK=32, 256 threads (4 waves, 2x2), 4x4 16x16x32 MFMA frags per wave.
__global__ __launch_bounds__(256) void k_gemm(const short* __restrict__ A,
                                              const short* __restrict__ B,
                                              float* __restrict__ C) {
    __shared__ short As[128 * 32];   // 8 KB, row-major [128][32], row stride 64B
    __shared__ short Bs[128 * 32];   // 8 KB

    const int bid = blockIdx.x;
    const int bn  = bid % 15;        // N tiles: 15 (covers padded 1920)
    const int bm  = bid / 15;
    const int t   = threadIdx.x;
    const int w   = t >> 6;
    const int l   = t & 63;
    const int wr  = w >> 1, wc = w & 1;

    // staging: chunk i (i=0,1) covers rows i*64 + w*16 + (l>>2), colbyte (l&3)*16
    const int srow  = w * 16 + (l >> 2);
    const int scolb = (l & 3) * 16;
    const char* gA = (const char*)(A + (long)(bm * 128 + srow) * KP) + scolb;
    const char* gB = (const char*)(B + (long)(bn * 128 + srow) * KP) + scolb;
    char* lA = (char*)As + w * 1024;
    char* lB = (char*)Bs + w * 1024;
    const long rowstep = (long)64 * KP * 2;   // 64 rows in bytes

    // fragment reads: lane l -> row (l&15), k-bytes (l>>4)*16 within [16][32] frag
    const int fr  = l & 15;
    const int fkb = (l >> 4) * 16;
    const char* rA = (const char*)As + (wr * 64 + fr) * 64 + fkb;
    const char* rB = (const char*)Bs + (wc * 64 + fr) * 64 + fkb;

    f32x4 acc[4][4] = {};

    for (int kt = 0; kt < KP / 32; ++kt) {
        const char* ga = gA + kt * 64;
        const char* gb = gB + kt * 64;
        gload_lds16(ga,           lA);
        gload_lds16(ga + rowstep, lA + 4096);
        gload_lds16(gb,           lB);
        gload_lds16(gb + rowstep, lB + 4096);
        __syncthreads();              // compiler drains vmcnt before barrier -> LDS ready

        bf16x8 af[4], bfr[4];
#pragma unroll
        for (int i = 0; i < 4; ++i) {
            af[i]  = *(const bf16x8*)(rA + i * 16 * 64);
            bfr[i] = *(const bf16x8*)(rB + i * 16 * 64);
        }
#pragma unroll
        for (int mi = 0; mi < 4; ++mi)
#pragma unroll
            for (int ni = 0; ni < 4; ++ni)
                acc[mi][ni] = __builtin_amdgcn_mfma_f32_16x16x32_bf16(
                    af[mi], bfr[ni], acc[mi][ni], 0, 0, 0);
        __syncthreads();              // all reads done before next overwrite
    }

    // epilogue: D frag (mi,ni): row = (l>>4)*4 + r, col = l&15  [m89-verified]
    const int col0 = bn * 128 + wc * 64 + fr;
    const int row0 = bm * 128 + wr * 64 + ((l >> 4) << 2);
#pragma unroll
    for (int ni = 0; ni < 4; ++ni) {
        int col = col0 + ni * 16;
        if (col < DIMV) {
#pragma unroll
            for (int mi = 0; mi < 4; ++mi) {
                long base = (long)(row0 + mi * 16) * DIMV + col;
#pragma unroll
                for (int r = 0; r < 4; ++r)
                    C[base + (long)r * DIMV] = BETA_F * acc[mi][ni][r];
            }
        }
    }
}

extern "C" void kernel_launch(void* const* d_in, const int* in_sizes, int n_in,
                              void* d_out, int out_size, void* d_ws, size_t ws_size,
                              hipStream_t stream) {
    const float* x    = (const float*)d_in[0];
    const int*   widx = (const int*)d_in[1];
    const float* wval = (const float*)d_in[2];
    float* out = (float*)d_out;

    const int nz = in_sizes[2];
    const int M  = in_sizes[0] / DIMV;      // 32768

    // workspace layout
    const size_t xb_bytes = (size_t)M * KP * 2;          // 125,829,120
    const size_t wb_bytes = (size_t)KP * KP * 2;         //   7,372,800
    const size_t wd_bytes = (size_t)DIMV * DIMV * 4;     //  14,592,400
    char* ws = (char*)d_ws;
    short* xb = (short*)ws;
    short* Wb = (short*)(ws + xb_bytes);
    float* Wd = (float*)(ws + xb_bytes + wb_bytes);
    if (ws_size < xb_bytes + wb_bytes + wd_bytes) return;   // insufficient scratch

    hipMemsetAsync(Wd, 0, wd_bytes, stream);
    k_scatter<<<(nz + 255) / 256, 256, 0, stream>>>(widx, widx + nz, wval, Wd, nz);
    k_build_w<<<dim3(KP / 128, KP), 128, 0, stream>>>(Wd, Wb);
    k_conv_x<<<dim3(KP / 128, M), 128, 0, stream>>>(x, xb);
    k_gemm<<<dim3(15 * (M / 128)), 256, 0, stream>>>(xb, Wb, out);
}

// Round 2
// 465.299 us; speedup vs baseline: 1.4332x; 1.4332x over previous
//
#include <hip/hip_runtime.h>
#include <hip/hip_bf16.h>
#include <stdint.h>

#define DIMV 1910
#define KP   1920                 // padded K (and W rows) — multiple of 64
#define NT   30                   // K tiles of 64
#define PHI_F  1.6180339887498949f
#define BETA_F 0.3819660112501051f

typedef __attribute__((ext_vector_type(4))) float f32x4;
typedef __attribute__((ext_vector_type(8))) short bf16x8;
typedef __attribute__((ext_vector_type(8))) unsigned short u16x8;

__device__ __forceinline__ void gl16(const void* g, void* l) {
    __builtin_amdgcn_global_load_lds(
        (const __attribute__((address_space(1))) void*)(uintptr_t)g,
        (__attribute__((address_space(3))) void*)(uint32_t)(uintptr_t)l,
        16, 0, 0);
}

__global__ void k_scatter(const int* __restrict__ ridx, const int* __restrict__ cidx,
                          const float* __restrict__ vals, float* __restrict__ Wd, int nz) {
    int i = blockIdx.x * 256 + threadIdx.x;
    if (i < nz) atomicAdd(Wd + (long)ridx[i] * DIMV + cidx[i], vals[i]);
}

// W' = W + PHI*I, padded to [KP][KP] bf16, vectorized ushort8 stores
__global__ void k_build_w(const float* __restrict__ Wd, unsigned short* __restrict__ Wb, int total8) {
    int stride = gridDim.x * blockDim.x;
    for (int i = blockIdx.x * blockDim.x + threadIdx.x; i < total8; i += stride) {
        int v = i * 8;
        int n = v / KP;
        int k = v - n * KP;
        u16x8 o;
#pragma unroll
        for (int j = 0; j < 8; ++j) {
            int kk = k + j;
            float fv = (n < DIMV && kk < DIMV) ? Wd[(size_t)n * DIMV + kk] : 0.f;
            if (kk == n && n < DIMV) fv += PHI_F;
            __hip_bfloat16 b = __float2bfloat16(fv);
            o[j] = *reinterpret_cast<unsigned short*>(&b);
        }
        *(u16x8*)(Wb + (size_t)v) = o;
    }
}

// x fp32 [M][1910] -> bf16 [M][1920], grid-stride, 8 elems/thread/iter
__global__ void k_conv_x(const float* __restrict__ x, unsigned short* __restrict__ xb, int total8) {
    int stride = gridDim.x * blockDim.x;
    for (int i = blockIdx.x * blockDim.x + threadIdx.x; i < total8; i += stride) {
        int v = i * 8;
        int row = v / KP;
        int col = v - row * KP;
        u16x8 o;
        if (col + 8 <= DIMV) {
            const float2* s = (const float2*)(x + (size_t)row * DIMV + col);
            float2 f0 = s[0], f1 = s[1], f2 = s[2], f3 = s[3];
            float f[8] = {f0.x, f0.y, f1.x, f1.y, f2.x, f2.y, f3.x, f3.y};
#pragma unroll
            for (int j = 0; j < 8; ++j) {
                __hip_bfloat16 b = __float2bfloat16(f[j]);
                o[j] = *reinterpret_cast<unsigned short*>(&b);
            }
        } else {
#pragma unroll
            for (int j = 0; j < 8; ++j) {
                int c = col + j;
                float fv = (c < DIMV) ? x[(size_t)row * DIMV + c] : 0.f;
                __hip_bfloat16 b = __float2bfloat16(fv);
                o[j] = *reinterpret_cast<unsigned short*>(&b);
            }
        }
        *(u16x8*)(xb + (size_t)v) = o;
    }
}

// C[m][n] = BETA * sum_k A[m][k] * B[n][k]
// A: [32768][1920] bf16, B: [1920][1920] bf16, C: [32768][1910] fp32
// Tile 256x128, BK=64, 512 threads (8 waves: 4M x 2N), per-wave 64x64 (4x4 frags).
// LDS: A 3-buf x 32KB + B 3-buf x 16KB = 144KB. Stage distance 2 tiles,
// counted vmcnt(6) once per tile (6 loads/tile: A=4, B=2). XOR-swizzled 16B slots.
__global__ __launch_bounds__(512, 2) void k_gemm(const short* __restrict__ A,
                                                 const short* __restrict__ B,
                                                 float* __restrict__ C) {
    __shared__ short As[3 * 256 * 64];   // 96 KB
    __shared__ short Bs[3 * 128 * 64];   // 48 KB

    // XCD-aware swizzle: grid 1920 = 8 XCDs * 240; bn-fastest within a chunk
    // so the 15 blocks sharing an A-panel sit on one XCD's L2.
    const int bid = blockIdx.x;
    const int logical = (bid & 7) * 240 + (bid >> 3);
    const int bm = logical / 15;
    const int bn = logical % 15;

    const int tid = threadIdx.x;
    const int w   = tid >> 6;
    const int l   = tid & 63;
    const int wr  = w >> 1;        // 0..3 (M)
    const int wc  = w & 1;         // 0..1 (N)
    const int fr  = l & 15;
    const int q   = l >> 4;        // 0..3

    // ---- staging (pre-swizzled global source, linear LDS dest) ----
    const int srow  = tid >> 3;                  // 0..63 within a 64-row group
    const int sslot = (tid & 7) ^ (srow & 7);    // inverse-swizzled 16B slot
    const char* aG = (const char*)A + ((size_t)(bm * 256 + srow) * KP) * 2 + sslot * 16;
    const char* bG = (const char*)B + ((size_t)(bn * 128 + srow) * KP) * 2 + sslot * 16;
    const size_t gstep = (size_t)64 * KP * 2;    // 64 global rows
    char* aL = (char*)As + tid * 16;
    char* bL = (char*)Bs + tid * 16;

    // ---- fragment read bases (swizzled) ----
    const int aBase = (wr * 64 + fr) * 128;      // bytes within an A buffer
    const int bBase = (wc * 64 + fr) * 128;
    const int co0 = ((q    ) ^ (fr & 7)) * 16;   // kk=0 swizzled slot offset
    const int co1 = ((q + 4) ^ (fr & 7)) * 16;   // kk=1

    f32x4 acc[4][4] = {};

    // ---- prologue: stage tiles 0 and 1 (12 loads), wait for tile 0 (oldest 6) ----
#pragma unroll
    for (int g = 0; g < 4; ++g) gl16(aG + g * gstep, aL + g * 8192);
#pragma unroll
    for (int g = 0; g < 2; ++g) gl16(bG + g * gstep, bL + g * 8192);
#pragma unroll
    for (int g = 0; g < 4; ++g) gl16(aG + 128 + g * gstep, aL + 32768 + g * 8192);
#pragma unroll
    for (int g = 0; g < 2; ++g) gl16(bG + 128 + g * gstep, bL + 16384 + g * 8192);
    asm volatile("s_waitcnt vmcnt(6)" ::: "memory");
    __builtin_amdgcn_s_barrier();
    asm volatile("" ::: "memory");

    int aRd = 0, bRd = 0;                    // read buffer byte offsets (t%3)
    int aSt = 2 * 32768, bSt = 2 * 16384;    // stage buffer byte offsets ((t+2)%3)

#pragma unroll 3
    for (int t = 0; t < NT; ++t) {
        const char* pa = (const char*)As + aRd + aBase;
        const char* pb = (const char*)Bs + bRd + bBase;

        // ---- P1: ds_read A(4mi x 2kk) + B(ni0-1 x 2kk); stage A(t+2); MFMA Q0 ----
        bf16x8 af[4][2], b0[2][2];
#pragma unroll
        for (int mi = 0; mi < 4; ++mi) {
            af[mi][0] = *(const bf16x8*)(pa + mi * 2048 + co0);
            af[mi][1] = *(const bf16x8*)(pa + mi * 2048 + co1);
        }
#pragma unroll
        for (int ni = 0; ni < 2; ++ni) {
            b0[ni][0] = *(const bf16x8*)(pb + ni * 2048 + co0);
            b0[ni][1] = *(const bf16x8*)(pb + ni * 2048 + co1);
        }
        if (t + 2 < NT) {
            const char* g = aG + (size_t)(t + 2) * 128;
#pragma unroll
            for (int gi = 0; gi < 4; ++gi) gl16(g + gi * gstep, aL + aSt + gi * 8192);
        }
        asm volatile("" ::: "memory");
        __builtin_amdgcn_s_barrier();
        asm volatile("" ::: "memory");
        __builtin_amdgcn_s_setprio(1);
#pragma unroll
        for (int mi = 0; mi < 4; ++mi)
#pragma unroll
            for (int ni = 0; ni < 2; ++ni) {
                acc[mi][ni] = __builtin_amdgcn_mfma_f32_16x16x32_bf16(af[mi][0], b0[ni][0], acc[mi][ni], 0, 0, 0);
                acc[mi][ni] = __builtin_amdgcn_mfma_f32_16x16x32_bf16(af[mi][1], b0[ni][1], acc[mi][ni], 0, 0, 0);
            }
        __builtin_amdgcn_s_setprio(0);
        asm volatile("" ::: "memory");
        __builtin_amdgcn_s_barrier();
        asm volatile("" ::: "memory");

        // ---- P2: ds_read B(ni2-3); stage B(t+2); counted vmcnt; MFMA Q1 ----
        bf16x8 b1[2][2];
#pragma unroll
        for (int ni = 0; ni < 2; ++ni) {
            b1[ni][0] = *(const bf16x8*)(pb + (ni + 2) * 2048 + co0);
            b1[ni][1] = *(const bf16x8*)(pb + (ni + 2) * 2048 + co1);
        }
        if (t + 2 < NT) {
            const char* g = bG + (size_t)(t + 2) * 128;
#pragma unroll
            for (int gi = 0; gi < 2; ++gi) gl16(g + gi * gstep, bL + bSt + gi * 8192);
            // tile t+1 (6 loads, issued last tile) must complete; tile t+2's 6 stay in flight
            asm volatile("s_waitcnt vmcnt(6)" ::: "memory");
        } else {
            asm volatile("s_waitcnt vmcnt(0)" ::: "memory");
        }
        __builtin_amdgcn_s_barrier();
        asm volatile("" ::: "memory");
        __builtin_amdgcn_s_setprio(1);
#pragma unroll
        for (int mi = 0; mi < 4; ++mi)
#pragma unroll
            for (int ni = 0; ni < 2; ++ni) {
                acc[mi][ni + 2] = __builtin_amdgcn_mfma_f32_16x16x32_bf16(af[mi][0], b1[ni][0], acc[mi][ni + 2], 0, 0, 0);
                acc[mi][ni + 2] = __builtin_amdgcn_mfma_f32_16x16x32_bf16(af[mi][1], b1[ni][1], acc[mi][ni + 2], 0, 0, 0);
            }
        __builtin_amdgcn_s_setprio(0);
        asm volatile("" ::: "memory");
        __builtin_amdgcn_s_barrier();
        asm volatile("" ::: "memory");

        aRd += 32768; if (aRd == 98304) aRd = 0;
        bRd += 16384; if (bRd == 49152) bRd = 0;
        aSt += 32768; if (aSt == 98304) aSt = 0;
        bSt += 16384; if (bSt == 49152) bSt = 0;
    }

    // ---- epilogue: C/D frag row = q*4 + r, col = fr (m89-verified) ----
    const int grow0 = bm * 256 + wr * 64 + q * 4;
    const int gcol0 = bn * 128 + wc * 64 + fr;
#pragma unroll
    for (int mi = 0; mi < 4; ++mi) {
#pragma unroll
        for (int ni = 0; ni < 4; ++ni) {
            int gcol = gcol0 + ni * 16;
            if (gcol < DIMV) {
                size_t base = (size_t)(grow0 + mi * 16) * DIMV + gcol;
#pragma unroll
                for (int r = 0; r < 4; ++r)
                    C[base + (size_t)r * DIMV] = BETA_F * acc[mi][ni][r];
            }
        }
    }
}

extern "C" void kernel_launch(void* const* d_in, const int* in_sizes, int n_in,
                              void* d_out, int out_size, void* d_ws, size_t ws_size,
                              hipStream_t stream) {
    const float* x    = (const float*)d_in[0];
    const int*   widx = (const int*)d_in[1];
    const float* wval = (const float*)d_in[2];
    float* out = (float*)d_out;

    const int nz = in_sizes[2];
    const int M  = in_sizes[0] / DIMV;      // 32768

    const size_t xb_bytes = (size_t)M * KP * 2;          // 125,829,120
    const size_t wb_bytes = (size_t)KP * KP * 2;         //   7,372,800
    const size_t wd_bytes = (size_t)DIMV * DIMV * 4;     //  14,592,400
    char* ws = (char*)d_ws;
    unsigned short* xb = (unsigned short*)ws;
    unsigned short* Wb = (unsigned short*)(ws + xb_bytes);
    float*          Wd = (float*)(ws + xb_bytes + wb_bytes);
    if (ws_size < xb_bytes + wb_bytes + wd_bytes) return;

    hipMemsetAsync(Wd, 0, wd_bytes, stream);
    k_scatter<<<(nz + 255) / 256, 256, 0, stream>>>(widx, widx + nz, wval, Wd, nz);
    k_build_w<<<1800, 256, 0, stream>>>(Wd, Wb, KP * KP / 8);
    k_conv_x<<<2048, 256, 0, stream>>>(x, xb, M * KP / 8);
    k_gemm<<<1920, 512, 0, stream>>>((const short*)xb, (const short*)Wb, out);
}